// Round 3
// baseline (2232.196 us; speedup 1.0000x reference)
//
#include <hip/hip_runtime.h>
#include <hip/hip_bf16.h>
#include <cstdint>
#include <cstddef>

// AttentionModule N=65536, C=D=512, L=16.
// The L-expand makes softmax uniform (1/16) and all L columns identical, so
// the attention branch cancels exactly:
//   pos  = relu(features @ Wk^T)
//   hmid = relu(bn1(features2 @ Wv1^T))
//   out  = relu(bn2(hmid @ Wv2^T)) + sigmoid(pos @ Wvc^T) * pos
// Wa / Wqk are mathematically unused. I/O fp32; compute bf16 MFMA, fp32 accum.
//
// K-loop: reg-staged prefetch (depth 2) + LDS double-buffer + ONE barrier per
// iteration. Loads for tile k+2 issue at iter k and are only waited on at the
// ds_write in iter k+1 (after compute) -> ~1.5 iterations of latency window,
// vs 0 with global_load_lds + __syncthreads drain.
#define DIM 512
#define NROWS 65536
#define NKT 16  // K tiles of 32

typedef __bf16 bf16;
typedef __attribute__((ext_vector_type(8))) __bf16 bf16x8;
typedef __attribute__((ext_vector_type(4))) __bf16 bf16x4;
typedef __attribute__((ext_vector_type(4))) float f32x4;

__device__ __forceinline__ float sigmoidf_(float x) {
  return 1.0f / (1.0f + __expf(-x));
}

// Block swizzle: the 4 n-tiles of one A row-strip get consecutive linear ids
// with the same (id % 8) -> same XCD under round-robin dispatch, so the A
// strip is fetched into that XCD's L2 once. Perf heuristic only.
__device__ __forceinline__ void swizzle(int id, int& m0, int& n0) {
  int xcd = id & 7;
  int q = id >> 3;                 // 0..255
  m0 = ((q >> 2) * 8 + xcd) * 128; // strip 0..511
  n0 = (q & 3) * 128;              // n-tile 0..3
}

// Pipelined 128x128x512 GEMM tile: acc += A[m0+128][512] * W[n0+128][512]^T
// (both k-contiguous). AF32: A is fp32, converted to bf16 in registers.
template <bool AF32>
__device__ __forceinline__ void gemm_loop(
    const void* __restrict__ Av, const bf16* __restrict__ W, int m0, int n0,
    bf16* AsmB, bf16* BsmB, f32x4 (&acc)[4][4]) {
  const int t = threadIdx.x;
  const int lane = t & 63;
  const int wv = t >> 6;
  const int wm = (wv & 1) * 64;
  const int wn = (wv >> 1) * 64;
  const int lr = lane & 15;
  const int kq = lane >> 4;

  // Staging mapping: thread t covers tile row ra = t>>1, k-half ca = (t&1)*16.
  const int ra = t >> 1;
  const int ca = (t & 1) * 16;
  const float* gAf = nullptr;
  const bf16* gAh = nullptr;
  if constexpr (AF32)
    gAf = (const float*)Av + (size_t)(m0 + ra) * DIM + ca;
  else
    gAh = (const bf16*)Av + (size_t)(m0 + ra) * DIM + ca;
  const bf16* gB = W + (size_t)(n0 + ra) * DIM + ca;
  const int lofs = ra * 32 + ca;

  f32x4 aF[2][4];
  bf16x8 aH[2][2];
  bf16x8 bR[2][2];

  auto load_t = [&](int kt, int s) {
    const int kb = kt * 32;
    if constexpr (AF32) {
      const f32x4* p = (const f32x4*)(gAf + kb);
      aF[s][0] = p[0]; aF[s][1] = p[1]; aF[s][2] = p[2]; aF[s][3] = p[3];
    } else {
      const bf16x8* p = (const bf16x8*)(gAh + kb);
      aH[s][0] = p[0]; aH[s][1] = p[1];
    }
    const bf16x8* pb = (const bf16x8*)(gB + kb);
    bR[s][0] = pb[0]; bR[s][1] = pb[1];
  };
  auto write_t = [&](int buf, int s) {
    bf16* la = AsmB + buf * (128 * 32) + lofs;
    if constexpr (AF32) {
      bf16x8 w0, w1;
#pragma unroll
      for (int j = 0; j < 4; j++) {
        w0[j] = (bf16)aF[s][0][j]; w0[j + 4] = (bf16)aF[s][1][j];
        w1[j] = (bf16)aF[s][2][j]; w1[j + 4] = (bf16)aF[s][3][j];
      }
      *(bf16x8*)la = w0; *(bf16x8*)(la + 8) = w1;
    } else {
      *(bf16x8*)la = aH[s][0]; *(bf16x8*)(la + 8) = aH[s][1];
    }
    bf16* lb = BsmB + buf * (128 * 32) + lofs;
    *(bf16x8*)lb = bR[s][0]; *(bf16x8*)(lb + 8) = bR[s][1];
  };

  // Prologue: tile0 -> LDS buf0; tile1 -> regs set1.
  load_t(0, 0);
  write_t(0, 0);
  load_t(1, 1);
  __syncthreads();

  for (int k = 0; k < NKT; k++) {
    const int p = k & 1;
    if (k + 2 < NKT) load_t(k + 2, k & 1);  // issue early, waited next iter

    bf16x8 af[4], bf_[4];
#pragma unroll
    for (int i = 0; i < 4; i++) {
      af[i]  = *(const bf16x8*)(AsmB + p * (128 * 32) + (wm + i * 16 + lr) * 32 + kq * 8);
      bf_[i] = *(const bf16x8*)(BsmB + p * (128 * 32) + (wn + i * 16 + lr) * 32 + kq * 8);
    }
#pragma unroll
    for (int i = 0; i < 4; i++)
#pragma unroll
      for (int j = 0; j < 4; j++)
        acc[i][j] = __builtin_amdgcn_mfma_f32_16x16x32_bf16(af[i], bf_[j],
                                                            acc[i][j], 0, 0, 0);
    if (k + 1 < NKT) {
      write_t(p ^ 1, (k + 1) & 1);  // regs loaded at iter k-1
      __syncthreads();              // single barrier per iteration
    }
  }
}

__device__ __forceinline__ void zero_acc(f32x4 (&acc)[4][4]) {
#pragma unroll
  for (int i = 0; i < 4; i++)
#pragma unroll
    for (int j = 0; j < 4; j++) acc[i][j] = (f32x4){0.f, 0.f, 0.f, 0.f};
}

// K1 (EPI=0): pos = relu(features @ Wk^T)          -> bf16
// K3 (EPI=2): hmid = relu(bn1(features2 @ Wv1^T))  -> bf16
template <int EPI>
__global__ __launch_bounds__(256) void gemm_k13(
    const float* __restrict__ A, const bf16* __restrict__ W,
    bf16* __restrict__ Out, const float* __restrict__ bn_g,
    const float* __restrict__ bn_b, const float* __restrict__ bn_m,
    const float* __restrict__ bn_v) {
  __shared__ bf16 Asm[2 * 128 * 32];
  __shared__ bf16 Bsm[2 * 128 * 32];
  int m0, n0;
  swizzle(blockIdx.x, m0, n0);

  f32x4 acc[4][4];
  zero_acc(acc);
  gemm_loop<true>(A, W, m0, n0, Asm, Bsm, acc);

  const int lane = threadIdx.x & 63;
  const int wv = threadIdx.x >> 6;
  const int wm = (wv & 1) * 64, wn = (wv >> 1) * 64;
  const int lr = lane & 15, kq = lane >> 4;

  float invj[4], bbj[4];
  if (EPI == 2) {
#pragma unroll
    for (int j = 0; j < 4; j++) {
      int c = n0 + wn + j * 16 + lr;
      float iv = bn_g[c] * rsqrtf(bn_v[c] + 1e-5f);
      invj[j] = iv;
      bbj[j] = bn_b[c] - bn_m[c] * iv;
    }
  }
#pragma unroll
  for (int i = 0; i < 4; i++) {
#pragma unroll
    for (int r = 0; r < 4; r++) {
      size_t row = (size_t)(m0 + wm + i * 16 + kq * 4 + r) * DIM;
#pragma unroll
      for (int j = 0; j < 4; j++) {
        int c = n0 + wn + j * 16 + lr;
        float v = acc[i][j][r];
        if (EPI == 0) v = fmaxf(v, 0.f);
        else          v = fmaxf(v * invj[j] + bbj[j], 0.f);
        Out[row + c] = (bf16)v;
      }
    }
  }
}

// Fused K2+K4: out = relu(bn2(hmid @ Wv2^T)) + sigmoid(pos @ Wvc^T) * pos
__global__ __launch_bounds__(256) void gemm_fused(
    const bf16* __restrict__ hmid, const bf16* __restrict__ pos,
    const bf16* __restrict__ Wv2b, const bf16* __restrict__ Wvcb,
    float* __restrict__ Out, const float* __restrict__ g2,
    const float* __restrict__ b2, const float* __restrict__ m2,
    const float* __restrict__ v2) {
  __shared__ bf16 Asm[2 * 128 * 32];
  __shared__ bf16 Bsm[2 * 128 * 32];
  int m0, n0;
  swizzle(blockIdx.x, m0, n0);

  const int lane = threadIdx.x & 63;
  const int wv = threadIdx.x >> 6;
  const int wm = (wv & 1) * 64, wn = (wv >> 1) * 64;
  const int lr = lane & 15, kq = lane >> 4;

  // GEMM 1: acc = hmid @ Wv2^T ; vout = relu(bn2(acc))
  f32x4 acc[4][4];
  zero_acc(acc);
  gemm_loop<false>(hmid, Wv2b, m0, n0, Asm, Bsm, acc);

  f32x4 vout[4][4];
#pragma unroll
  for (int j = 0; j < 4; j++) {
    int c = n0 + wn + j * 16 + lr;
    float iv = g2[c] * rsqrtf(v2[c] + 1e-5f);
    float bb = b2[c] - m2[c] * iv;
#pragma unroll
    for (int i = 0; i < 4; i++)
#pragma unroll
      for (int r = 0; r < 4; r++)
        vout[i][j][r] = fmaxf(acc[i][j][r] * iv + bb, 0.f);
  }

  // GEMM 2: acc = pos @ Wvc^T. Safe without an extra barrier: its prologue
  // barrier orders all LDS writes after every wave finished GEMM 1.
  zero_acc(acc);
  gemm_loop<false>(pos, Wvcb, m0, n0, Asm, Bsm, acc);

#pragma unroll
  for (int i = 0; i < 4; i++) {
#pragma unroll
    for (int r = 0; r < 4; r++) {
      size_t row = (size_t)(m0 + wm + i * 16 + kq * 4 + r) * DIM;
#pragma unroll
      for (int j = 0; j < 4; j++) {
        int c = n0 + wn + j * 16 + lr;
        float pv = sigmoidf_(acc[i][j][r]) * (float)pos[row + c];
        Out[row + c] = vout[i][j][r] + pv;
      }
    }
  }
}

// Convert the 4 weight matrices (512x512 fp32) to bf16. 256 blocks/weight.
__global__ __launch_bounds__(256) void cvt_w(
    const float* __restrict__ s0, const float* __restrict__ s1,
    const float* __restrict__ s2, const float* __restrict__ s3,
    bf16* __restrict__ d0, bf16* __restrict__ d1, bf16* __restrict__ d2,
    bf16* __restrict__ d3) {
  int w = blockIdx.x >> 8;
  int i = (blockIdx.x & 255) * 256 + threadIdx.x;
  const float* s = w == 0 ? s0 : w == 1 ? s1 : w == 2 ? s2 : s3;
  bf16* d = w == 0 ? d0 : w == 1 ? d1 : w == 2 ? d2 : d3;
  f32x4 v = ((const f32x4*)s)[i];
  bf16x4 o;
  o[0] = (bf16)v[0]; o[1] = (bf16)v[1]; o[2] = (bf16)v[2]; o[3] = (bf16)v[3];
  ((bf16x4*)d)[i] = o;
}

extern "C" void kernel_launch(void* const* d_in, const int* in_sizes, int n_in,
                              void* d_out, int out_size, void* d_ws,
                              size_t ws_size, hipStream_t stream) {
  const float* features  = (const float*)d_in[0];
  const float* features2 = (const float*)d_in[1];
  const float* Wk  = (const float*)d_in[2];
  const float* Wv1 = (const float*)d_in[3];
  const float* Wv2 = (const float*)d_in[4];
  const float* g1 = (const float*)d_in[5];
  const float* b1 = (const float*)d_in[6];
  const float* m1 = (const float*)d_in[7];
  const float* v1 = (const float*)d_in[8];
  const float* g2 = (const float*)d_in[9];
  const float* b2 = (const float*)d_in[10];
  const float* m2 = (const float*)d_in[11];
  const float* v2 = (const float*)d_in[12];
  // d_in[13] Wa, d_in[14] Wqk: cancelled, unused.
  const float* Wvc = (const float*)d_in[15];
  float* out = (float*)d_out;

  // ws (bf16): pos | hmid | wk | wv1 | wv2 | wvc  ~= 130 MiB.
  bf16* pos  = (bf16*)d_ws;
  bf16* hmid = pos + (size_t)NROWS * DIM;
  bf16* wkb  = hmid + (size_t)NROWS * DIM;
  bf16* wv1b = wkb + DIM * DIM;
  bf16* wv2b = wv1b + DIM * DIM;
  bf16* wvcb = wv2b + DIM * DIM;

  cvt_w<<<1024, 256, 0, stream>>>(Wk, Wv1, Wv2, Wvc, wkb, wv1b, wv2b, wvcb);

  // 2048 blocks: (row-strip 0..511) x (n-tile 0..3), XCD-swizzled.
  gemm_k13<0><<<2048, 256, 0, stream>>>(features, wkb, pos,
                                        nullptr, nullptr, nullptr, nullptr);
  gemm_k13<2><<<2048, 256, 0, stream>>>(features2, wv1b, hmid, g1, b1, m1, v1);
  gemm_fused<<<2048, 256, 0, stream>>>(hmid, pos, wv2b, wvcb, out,
                                       g2, b2, m2, v2);
}